// Round 4
// baseline (981.532 us; speedup 1.0000x reference)
//
#include <hip/hip_runtime.h>
#include <hip/hip_bf16.h>

#define N_NODES  50000
#define N_EDGES  800000
#define NDIM_IN  64
#define EDIMS    64
#define NDIM_OUT 128

typedef __bf16 bf16;
typedef bf16  bf16x8 __attribute__((ext_vector_type(8)));
typedef float f32x4  __attribute__((ext_vector_type(4)));

// ---------------------------------------------------------------------------
// Runtime dtype detection (harness dtype is ambiguous; we guard both ways).
// ---------------------------------------------------------------------------
__device__ __forceinline__ bool detect_f32(const void* nfeats) {
    const unsigned short* w = (const unsigned short*)nfeats;
    for (int i = 0; i < 64; i += 2) {
        const int e = (w[i] >> 7) & 0xFF;
        if (e < 100 || e > 134) return true;
    }
    return false;
}
__device__ __forceinline__ bool detect_i64(const int* p) {
    for (int i = 1; i < 64; i += 2) if (p[i] != 0) return false;
    return true;
}

__device__ __forceinline__ bf16x8 load8(const void* p, long off, bool f32) {
    if (f32) {
        const float* q = (const float*)p + off;
        const f32x4 a = *(const f32x4*)q;
        const f32x4 b = *(const f32x4*)(q + 4);
        bf16x8 r;
        #pragma unroll
        for (int u = 0; u < 4; ++u) { r[u] = (bf16)a[u]; r[4 + u] = (bf16)b[u]; }
        return r;
    }
    return *(const bf16x8*)((const bf16*)p + off);
}
__device__ __forceinline__ float loadf(const void* p, long i, bool f32) {
    return f32 ? ((const float*)p)[i] : (float)((const bf16*)p)[i];
}
__device__ __forceinline__ void storef(void* p, long i, float v, bool f32) {
    if (f32) ((float*)p)[i] = v; else ((bf16*)p)[i] = (bf16)v;
}

// ---------------------------------------------------------------------------
// nfeats -> bf16 table (coalesced convert). agg gathers x-fragments from this
// 6.4 MB (L2-resident) table; gather no longer touches nfeats at all.
// ---------------------------------------------------------------------------
__global__ __launch_bounds__(256) void nf2bf_kernel(const void* __restrict__ nfeats,
                                                    bf16* __restrict__ tbl) {
    __shared__ int s_flags;
    if (threadIdx.x == 0) s_flags = detect_f32(nfeats) ? 1 : 0;
    __syncthreads();
    const bool f32 = (s_flags & 1) != 0;
    const int total  = N_NODES * 64 / 8;          // 400000 chunks of 8
    const int stride = gridDim.x * blockDim.x;
    for (int i = blockIdx.x * blockDim.x + threadIdx.x; i < total; i += stride)
        *(bf16x8*)(tbl + (size_t)i * 8) = load8(nfeats, (long)i * 8, f32);
}

// ---------------------------------------------------------------------------
// CSR build step 1: histogram over dst.
// ---------------------------------------------------------------------------
__global__ __launch_bounds__(256) void hist_kernel(const int* __restrict__ dst,
                                                   int* __restrict__ cnt) {
    __shared__ int s_ish;
    if (threadIdx.x == 0) s_ish = detect_i64(dst) ? 1 : 0;
    __syncthreads();
    const int ish = s_ish;
    const int stride = gridDim.x * blockDim.x;
    for (int e = blockIdx.x * blockDim.x + threadIdx.x; e < N_EDGES; e += stride)
        atomicAdd(&cnt[dst[(long)e << ish]], 1);
}

// ---------------------------------------------------------------------------
// CSR build step 2: exclusive scan of counts (padded to 53248 = 1024*52 ints,
// pad region pre-zeroed). int4 loads + shfl wave scans. Writes row_ptr[] and
// resets cnt[] in place to the running cursor for the gather pass.
// ---------------------------------------------------------------------------
__global__ __launch_bounds__(1024) void scan_kernel(int* __restrict__ cnt,
                                                    int* __restrict__ row_ptr) {
    __shared__ int sw[16];
    const int t    = threadIdx.x;
    const int lane = t & 63;
    const int w    = t >> 6;
    const int base = t * 52;

    int sum = 0;
    #pragma unroll
    for (int j = 0; j < 13; ++j) {
        const int4 q = *(const int4*)(cnt + base + j * 4);
        sum += q.x + q.y + q.z + q.w;
    }
    int s = sum;
    #pragma unroll
    for (int off = 1; off < 64; off <<= 1) {
        const int u = __shfl_up(s, off, 64);
        if (lane >= off) s += u;
    }
    if (lane == 63) sw[w] = s;
    __syncthreads();
    if (t < 16) {
        int x = sw[t];
        #pragma unroll
        for (int off = 1; off < 16; off <<= 1) {
            const int u = __shfl_up(x, off, 16);
            if ((t & 15) >= off) x += u;
        }
        sw[t] = x;
    }
    __syncthreads();
    int run = (w > 0 ? sw[w - 1] : 0) + (s - sum);
    #pragma unroll
    for (int j = 0; j < 13; ++j) {
        const int4 q = *(const int4*)(cnt + base + j * 4);
        int4 r;
        r.x = run; run += q.x;
        r.y = run; run += q.y;
        r.z = run; run += q.z;
        r.w = run; run += q.w;
        *(int4*)(row_ptr + base + j * 4) = r;
        *(int4*)(cnt     + base + j * 4) = r;
    }
}

// ---------------------------------------------------------------------------
// CSR build step 3: permute efeats into CSR order (128 B bf16 rows) and
// record srcs[] in CSR order. 8 lanes per edge -> every A store is a full
// 128 B line (no partial-line RMW). nfeats no longer gathered here.
// ---------------------------------------------------------------------------
__global__ __launch_bounds__(256) void gather_kernel(
    const void* __restrict__ efeats,
    const int*  __restrict__ src,
    const int*  __restrict__ dst,
    int*        __restrict__ cursor,
    bf16*       __restrict__ A,
    int*        __restrict__ srcs)
{
    __shared__ int s_flags;
    const int tid = threadIdx.x;
    if (tid == 0)
        s_flags = (detect_f32(efeats) ? 1 : 0) | (detect_i64(dst) ? 2 : 0);
    __syncthreads();
    const bool f32 = (s_flags & 1) != 0;
    const int  ish = (s_flags & 2) ? 1 : 0;

    const int lane = tid & 63;
    const int wave = tid >> 6;
    const int q    = lane & 7;    // 16 B chunk of the 128 B output row
    const int ei   = lane >> 3;   // edge within group of 8

    const int ngroups = N_EDGES / 8;          // 100000 exact
    const int nw      = gridDim.x * 4;
    for (int g = blockIdx.x * 4 + wave; g < ngroups; g += nw) {
        const int e = g * 8 + ei;
        int pos = 0, s_ = 0;
        if (q == 0) {
            pos = atomicAdd(&cursor[dst[(long)e << ish]], 1);
            s_  = src[(long)e << ish];
        }
        pos = __shfl(pos, lane & 56, 64);

        const bf16x8 v = load8(efeats, (long)e * 64 + q * 8, f32);
        *(bf16x8*)(A + (size_t)pos * 64 + q * 8) = v;
        if (q == 0) srcs[pos] = s_;
    }
}

// ---------------------------------------------------------------------------
// Dense fused message + aggregate, cross-node software pipelined.
// One wave per dst node; A = CSR-permuted efeats (streamed), x-fragments
// gathered from the L2-resident bf16 nfeats table. While computing node v's
// tile-0, the full load chain (row_ptr -> srcs -> frags) for node v+stride is
// already in flight -> next-node latency hides under current-node compute.
// ---------------------------------------------------------------------------
__global__ __launch_bounds__(256, 4) void msg_agg_dense(
    const void* __restrict__ nfeats,      // only for dtype detection
    const bf16* __restrict__ xtbl,        // [N][64] bf16
    const bf16* __restrict__ A,           // [E][64] bf16, CSR order
    const int*  __restrict__ srcs,        // [E] src id, CSR order
    const void* __restrict__ W_msg,
    const void* __restrict__ b_msg,
    const int*  __restrict__ row_ptr,
    float*      __restrict__ h_neigh)
{
    __shared__ bf16  sWT[128 * 136];      // [n][k], stride 272 B
    __shared__ float sB[128];
    __shared__ int   s_flags;

    const int tid = threadIdx.x;
    if (tid == 0) s_flags = detect_f32(nfeats) ? 1 : 0;
    __syncthreads();
    const bool f32 = (s_flags & 1) != 0;

    // k-strided staging: task -> (n = task&127, kb8 = task>>7), one b128 write
    #pragma unroll
    for (int it = 0; it < 8; ++it) {
        const int task = it * 256 + tid;
        const int n    = task & 127;
        const int kb8  = task >> 7;       // 0..15
        bf16x8 w;
        #pragma unroll
        for (int j = 0; j < 8; ++j)
            w[j] = (bf16)loadf(W_msg, (long)(kb8 * 8 + j) * 128 + n, f32);
        *(bf16x8*)(sWT + n * 136 + kb8 * 8) = w;
    }
    if (tid < 128) sB[tid] = loadf(b_msg, tid, f32);
    __syncthreads();

    const int wave = tid >> 6;
    const int lane = tid & 63;
    const int m    = lane & 15;
    const int quad = lane >> 4;

    const int wstride = gridDim.x * 4;
    int v = blockIdx.x * 4 + wave;
    if (v >= N_NODES) return;

    // prime the pipeline: current node's header + first-tile fragments
    int beg = row_ptr[v];
    int deg = row_ptr[v + 1] - beg;
    bf16x8 a0, a1, a2, a3;
    {
        int sl = beg + (m < deg ? m : 0);
        sl = sl < N_EDGES ? sl : N_EDGES - 1;       // deg==0 tail safety
        int s = srcs[sl];
        s = ((unsigned)s < N_NODES) ? s : 0;        // garbage-guard
        a2 = *(const bf16x8*)(A + (size_t)sl * 64 + quad * 8);
        a3 = *(const bf16x8*)(A + (size_t)sl * 64 + 32 + quad * 8);
        a0 = *(const bf16x8*)(xtbl + (size_t)s * 64 + quad * 8);
        a1 = *(const bf16x8*)(xtbl + (size_t)s * 64 + 32 + quad * 8);
    }

    while (true) {
        // ---- issue next node's full load chain before current compute ----
        const int  vn   = v + wstride;
        const bool hasn = vn < N_NODES;
        int begn = 0, degn = 0;
        bf16x8 b0, b1, b2, b3;
        if (hasn) {
            begn = row_ptr[vn];
            degn = row_ptr[vn + 1] - begn;
            int sln = begn + (m < degn ? m : 0);
            sln = sln < N_EDGES ? sln : N_EDGES - 1;
            int sn = srcs[sln];
            sn = ((unsigned)sn < N_NODES) ? sn : 0;
            b2 = *(const bf16x8*)(A + (size_t)sln * 64 + quad * 8);
            b3 = *(const bf16x8*)(A + (size_t)sln * 64 + 32 + quad * 8);
            b0 = *(const bf16x8*)(xtbl + (size_t)sn * 64 + quad * 8);
            b1 = *(const bf16x8*)(xtbl + (size_t)sn * 64 + 32 + quad * 8);
        }

        float hacc[8] = {0.f, 0.f, 0.f, 0.f, 0.f, 0.f, 0.f, 0.f};

        // ---- tile 0 (the common case: deg <= 16) ----
        #pragma unroll
        for (int t = 0; t < 8; ++t) {
            f32x4 acc = {0.f, 0.f, 0.f, 0.f};
            const bf16* bp = sWT + (t * 16 + m) * 136 + quad * 8;
            acc = __builtin_amdgcn_mfma_f32_16x16x32_bf16(a0, *(const bf16x8*)(bp      ), acc, 0, 0, 0);
            acc = __builtin_amdgcn_mfma_f32_16x16x32_bf16(a1, *(const bf16x8*)(bp +  32), acc, 0, 0, 0);
            acc = __builtin_amdgcn_mfma_f32_16x16x32_bf16(a2, *(const bf16x8*)(bp +  64), acc, 0, 0, 0);
            acc = __builtin_amdgcn_mfma_f32_16x16x32_bf16(a3, *(const bf16x8*)(bp +  96), acc, 0, 0, 0);
            const float bias = sB[t * 16 + m];
            float part = 0.f;
            #pragma unroll
            for (int i = 0; i < 4; ++i) {
                float val = acc[i] + bias;
                val = val > 0.f ? val : 0.f;
                if (quad * 4 + i < deg) part += val;
            }
            hacc[t] += part;
        }

        // ---- extra tiles (deg > 16), loaded on demand ----
        for (int T = 1; T * 16 < deg; ++T) {
            const int r0 = T * 16;
            const int sl = (r0 + m < deg) ? (beg + r0 + m) : beg;
            const int s  = srcs[sl];
            const bf16x8 c2 = *(const bf16x8*)(A + (size_t)sl * 64 + quad * 8);
            const bf16x8 c3 = *(const bf16x8*)(A + (size_t)sl * 64 + 32 + quad * 8);
            const bf16x8 c0 = *(const bf16x8*)(xtbl + (size_t)s * 64 + quad * 8);
            const bf16x8 c1 = *(const bf16x8*)(xtbl + (size_t)s * 64 + 32 + quad * 8);
            #pragma unroll
            for (int t = 0; t < 8; ++t) {
                f32x4 acc = {0.f, 0.f, 0.f, 0.f};
                const bf16* bp = sWT + (t * 16 + m) * 136 + quad * 8;
                acc = __builtin_amdgcn_mfma_f32_16x16x32_bf16(c0, *(const bf16x8*)(bp      ), acc, 0, 0, 0);
                acc = __builtin_amdgcn_mfma_f32_16x16x32_bf16(c1, *(const bf16x8*)(bp +  32), acc, 0, 0, 0);
                acc = __builtin_amdgcn_mfma_f32_16x16x32_bf16(c2, *(const bf16x8*)(bp +  64), acc, 0, 0, 0);
                acc = __builtin_amdgcn_mfma_f32_16x16x32_bf16(c3, *(const bf16x8*)(bp +  96), acc, 0, 0, 0);
                const float bias = sB[t * 16 + m];
                float part = 0.f;
                #pragma unroll
                for (int i = 0; i < 4; ++i) {
                    float val = acc[i] + bias;
                    val = val > 0.f ? val : 0.f;
                    if (r0 + quad * 4 + i < deg) part += val;
                }
                hacc[t] += part;
            }
        }

        // ---- cross-quad column reduction + coalesced store ----
        #pragma unroll
        for (int t = 0; t < 8; ++t) {
            float s = hacc[t];
            s += __shfl_xor(s, 16, 64);
            s += __shfl_xor(s, 32, 64);
            hacc[t] = s;
        }
        const float lo = quad < 2 ? (quad == 0 ? hacc[0] : hacc[1])
                                  : (quad == 2 ? hacc[2] : hacc[3]);
        const float hi = quad < 2 ? (quad == 0 ? hacc[4] : hacc[5])
                                  : (quad == 2 ? hacc[6] : hacc[7]);
        h_neigh[(size_t)v * 128 + lane]      = lo;
        h_neigh[(size_t)v * 128 + 64 + lane] = hi;

        if (!hasn) break;
        v = vn; beg = begn; deg = degn;
        a0 = b0; a1 = b1; a2 = b2; a3 = b3;
    }
}

// ---------------------------------------------------------------------------
// Fallback CSR path (verified round-1): scatter edge ids, gather in msg_agg.
// ---------------------------------------------------------------------------
__global__ __launch_bounds__(256) void scatter_kernel(const int* __restrict__ src,
                                                      const int* __restrict__ dst,
                                                      int* __restrict__ cursor,
                                                      int* __restrict__ eid,
                                                      int* __restrict__ srcs) {
    __shared__ int s_ish;
    if (threadIdx.x == 0) s_ish = detect_i64(dst) ? 1 : 0;
    __syncthreads();
    const int ish = s_ish;
    const int stride = gridDim.x * blockDim.x;
    for (int e = blockIdx.x * blockDim.x + threadIdx.x; e < N_EDGES; e += stride) {
        const int d = dst[(long)e << ish];
        const int pos = atomicAdd(&cursor[d], 1);
        eid[pos]  = e;
        srcs[pos] = src[(long)e << ish];
    }
}

__global__ __launch_bounds__(256) void msg_agg_kernel(
    const void* __restrict__ nfeats,
    const void* __restrict__ efeats,
    const void* __restrict__ W_msg,
    const void* __restrict__ b_msg,
    const int*  __restrict__ row_ptr,
    const int*  __restrict__ eid,
    const int*  __restrict__ srcs,
    float*      __restrict__ h_neigh)
{
    __shared__ bf16 sWT[128 * 136];
    __shared__ int s_flags;

    const int tid = threadIdx.x;
    if (tid == 0) s_flags = detect_f32(nfeats) ? 1 : 0;
    __syncthreads();
    const bool f32 = (s_flags & 1) != 0;

    #pragma unroll
    for (int it = 0; it < 8; ++it) {
        const int task = it * 256 + tid;
        const int k = task >> 4;
        const int c = task & 15;
        const bf16x8 w = load8(W_msg, (long)k * 128 + c * 8, f32);
        #pragma unroll
        for (int u = 0; u < 8; ++u) sWT[(c * 8 + u) * 136 + k] = w[u];
    }
    __syncthreads();

    const int wave = tid >> 6;
    const int lane = tid & 63;
    const int m    = lane & 15;
    const int quad = lane >> 4;

    float bias[8];
    #pragma unroll
    for (int t = 0; t < 8; ++t) bias[t] = loadf(b_msg, t * 16 + m, f32);

    const int wstride = gridDim.x * 4;
    for (int v = blockIdx.x * 4 + wave; v < N_NODES; v += wstride) {
        const int beg = row_ptr[v];
        const int deg = row_ptr[v + 1] - beg;

        float hacc[8] = {0.f, 0.f, 0.f, 0.f, 0.f, 0.f, 0.f, 0.f};

        for (int T = 0; T * 16 < deg; ++T) {
            const int r0 = T * 16;
            const int sl = (r0 + m < deg) ? (beg + r0 + m) : beg;
            const int s  = srcs[sl];
            const int e  = eid[sl];

            bf16x8 a[4];
            a[0] = load8(nfeats, (long)s * 64 +      quad * 8, f32);
            a[1] = load8(nfeats, (long)s * 64 + 32 + quad * 8, f32);
            a[2] = load8(efeats, (long)e * 64 +      quad * 8, f32);
            a[3] = load8(efeats, (long)e * 64 + 32 + quad * 8, f32);

            #pragma unroll
            for (int t = 0; t < 8; ++t) {
                f32x4 acc = {0.f, 0.f, 0.f, 0.f};
                const bf16* bp = sWT + (t * 16 + m) * 136 + quad * 8;
                #pragma unroll
                for (int kb = 0; kb < 4; ++kb)
                    acc = __builtin_amdgcn_mfma_f32_16x16x32_bf16(
                              a[kb], *(const bf16x8*)(bp + kb * 32), acc, 0, 0, 0);
                float part = 0.f;
                #pragma unroll
                for (int i = 0; i < 4; ++i) {
                    float val = acc[i] + bias[t];
                    val = val > 0.f ? val : 0.f;
                    if (r0 + quad * 4 + i < deg) part += val;
                }
                hacc[t] += part;
            }
        }

        #pragma unroll
        for (int t = 0; t < 8; ++t) {
            float s = hacc[t];
            s += __shfl_xor(s, 16, 64);
            s += __shfl_xor(s, 32, 64);
            hacc[t] = s;
        }

        const float lo = quad < 2 ? (quad == 0 ? hacc[0] : hacc[1])
                                  : (quad == 2 ? hacc[2] : hacc[3]);
        const float hi = quad < 2 ? (quad == 0 ? hacc[4] : hacc[5])
                                  : (quad == 2 ? hacc[6] : hacc[7]);
        h_neigh[(size_t)v * 128 + lane]      = lo;
        h_neigh[(size_t)v * 128 + 64 + lane] = hi;
    }
}

// ---------------------------------------------------------------------------
// Last-resort fallback (verified round-0): per-edge messages + fp32 atomics.
// ---------------------------------------------------------------------------
__global__ __launch_bounds__(256) void edge_msg_kernel(
    const void* __restrict__ nfeats,
    const void* __restrict__ efeats,
    const void* __restrict__ W_msg,
    const void* __restrict__ b_msg,
    const int*  __restrict__ src,
    const int*  __restrict__ dst,
    float*      __restrict__ h_neigh)
{
    __shared__ bf16 sWT[128 * 136];
    __shared__ int s_flags;

    const int tid = threadIdx.x;
    if (tid == 0)
        s_flags = (detect_f32(nfeats) ? 1 : 0) | (detect_i64(dst) ? 2 : 0);
    __syncthreads();
    const bool f32 = (s_flags & 1) != 0;
    const int  ish = (s_flags & 2) ? 1 : 0;

    #pragma unroll
    for (int it = 0; it < 8; ++it) {
        const int task = it * 256 + tid;
        const int k = task >> 4;
        const int c = task & 15;
        const bf16x8 w = load8(W_msg, (long)k * 128 + c * 8, f32);
        #pragma unroll
        for (int u = 0; u < 8; ++u) sWT[(c * 8 + u) * 136 + k] = w[u];
    }
    __syncthreads();

    const int wave = tid >> 6;
    const int lane = tid & 63;
    const int m    = lane & 15;
    const int quad = lane >> 4;

    const int nchunks = N_EDGES / 64;
    for (int chunk = blockIdx.x; chunk < nchunks; chunk += gridDim.x) {
        const int ebase = chunk * 64 + wave * 16;
        const int e_m   = ebase + m;
        const int s     = src[(long)e_m << ish];

        bf16x8 a[4];
        a[0] = load8(nfeats, (long)s   * 64 +      quad * 8, f32);
        a[1] = load8(nfeats, (long)s   * 64 + 32 + quad * 8, f32);
        a[2] = load8(efeats, (long)e_m * 64 +      quad * 8, f32);
        a[3] = load8(efeats, (long)e_m * 64 + 32 + quad * 8, f32);

        int drow[4];
        #pragma unroll
        for (int i = 0; i < 4; ++i)
            drow[i] = dst[(long)(ebase + quad * 4 + i) << ish] * 128;

        #pragma unroll
        for (int t = 0; t < 8; ++t) {
            f32x4 acc = {0.f, 0.f, 0.f, 0.f};
            const bf16* bp = sWT + (t * 16 + m) * 136 + quad * 8;
            #pragma unroll
            for (int kb = 0; kb < 4; ++kb)
                acc = __builtin_amdgcn_mfma_f32_16x16x32_bf16(
                          a[kb], *(const bf16x8*)(bp + kb * 32), acc, 0, 0, 0);
            const int   n    = t * 16 + m;
            const float bias = loadf(b_msg, n, f32);
            #pragma unroll
            for (int i = 0; i < 4; ++i) {
                float v = acc[i] + bias;
                v = v > 0.f ? v : 0.f;
                unsafeAtomicAdd(h_neigh + drow[i] + n, v);
            }
        }
    }
}

// ---------------------------------------------------------------------------
// Kernel B: out = relu([nfeats, h_neigh] @ W_apply + b_apply), K=192.
// (unchanged from verified round-3 version)
// ---------------------------------------------------------------------------
__global__ __launch_bounds__(256) void apply_kernel(
    const void*  __restrict__ nfeats,
    const float* __restrict__ h_neigh,
    const void*  __restrict__ W_apply,
    const void*  __restrict__ b_apply,
    void*        __restrict__ out)
{
    __shared__ bf16 sWT[128 * 200];   // [n][k], k<192, stride 400 B
    __shared__ int s_flags;

    const int tid = threadIdx.x;
    if (tid == 0) s_flags = detect_f32(nfeats) ? 1 : 0;
    __syncthreads();
    const bool f32 = (s_flags & 1) != 0;

    // k-strided staging: 3072 tasks = 128 n x 24 kb8-blocks
    #pragma unroll
    for (int it = 0; it < 12; ++it) {
        const int task = it * 256 + tid;
        const int n    = task & 127;
        const int kb8  = task >> 7;       // 0..23
        bf16x8 w;
        #pragma unroll
        for (int j = 0; j < 8; ++j)
            w[j] = (bf16)loadf(W_apply, (long)(kb8 * 8 + j) * 128 + n, f32);
        *(bf16x8*)(sWT + n * 200 + kb8 * 8) = w;
    }
    __syncthreads();

    const int wave = tid >> 6;
    const int lane = tid & 63;
    const int m    = lane & 15;
    const int quad = lane >> 4;

    const int nchunks = (N_NODES + 63) / 64;
    for (int chunk = blockIdx.x; chunk < nchunks; chunk += gridDim.x) {
        const int nbase = chunk * 64 + wave * 16;
        const int nm  = nbase + m;
        const int nmc = nm < N_NODES ? nm : N_NODES - 1;

        bf16x8 a[6];
        a[0] = load8(nfeats, (long)nmc * 64 +      quad * 8, f32);
        a[1] = load8(nfeats, (long)nmc * 64 + 32 + quad * 8, f32);
        #pragma unroll
        for (int kb = 0; kb < 4; ++kb) {
            const float* hp = h_neigh + (size_t)nmc * 128 + kb * 32 + quad * 8;
            const f32x4 p = *(const f32x4*)(hp);
            const f32x4 q = *(const f32x4*)(hp + 4);
            bf16x8 r;
            #pragma unroll
            for (int u = 0; u < 4; ++u) { r[u] = (bf16)p[u]; r[4 + u] = (bf16)q[u]; }
            a[2 + kb] = r;
        }

        #pragma unroll
        for (int t = 0; t < 8; ++t) {
            f32x4 acc = {0.f, 0.f, 0.f, 0.f};
            const bf16* bp = sWT + (t * 16 + m) * 200 + quad * 8;
            #pragma unroll
            for (int kb = 0; kb < 6; ++kb)
                acc = __builtin_amdgcn_mfma_f32_16x16x32_bf16(
                          a[kb], *(const bf16x8*)(bp + kb * 32), acc, 0, 0, 0);
            const int   n    = t * 16 + m;
            const float bias = loadf(b_apply, n, f32);
            #pragma unroll
            for (int i = 0; i < 4; ++i) {
                const int row = nbase + quad * 4 + i;
                if (row < N_NODES) {
                    float v = acc[i] + bias;
                    v = v > 0.f ? v : 0.f;
                    storef(out, (long)row * 128 + n, v, f32);
                }
            }
        }
    }
}

extern "C" void kernel_launch(void* const* d_in, const int* in_sizes, int n_in,
                              void* d_out, int out_size, void* d_ws, size_t ws_size,
                              hipStream_t stream) {
    const void* nfeats  = d_in[0];
    const void* efeats  = d_in[1];
    const void* W_msg   = d_in[2];
    const void* b_msg   = d_in[3];
    const void* W_apply = d_in[4];
    const void* b_apply = d_in[5];
    const int*  src     = (const int*)d_in[6];
    const int*  dst     = (const int*)d_in[7];

    float* h_neigh = (float*)d_ws;                        // 25,600,000 B

    // workspace layout (256B-aligned blocks)
    const size_t SZ_PAD     = 213248;                     // 53248 ints, padded
    const size_t OFF_ROWPTR = 25600000;
    const size_t OFF_CNT    = OFF_ROWPTR + SZ_PAD;        // counts -> cursor
    const size_t OFF_XT     = OFF_CNT + SZ_PAD;           // bf16 nfeats table
    const size_t SZ_XT      = (size_t)N_NODES * 64 * 2;   // 6.4 MB
    const size_t OFF_A      = OFF_XT + SZ_XT;             // permuted efeats
    const size_t SZ_A       = (size_t)N_EDGES * 64 * 2;   // 102.4 MB
    const size_t OFF_SRCS   = OFF_A + SZ_A;               // CSR-ordered src
    const size_t NEED_DENSE = OFF_SRCS + 3200000;         // ~138 MB
    const size_t OFF_EID    = OFF_XT;                     // CSR fallback path
    const size_t OFF_SRCS2  = OFF_EID + 3200000;
    const size_t NEED_CSR   = OFF_SRCS2 + 3200000;        // 32.4 MB

    int* row_ptr = (int*)((char*)d_ws + OFF_ROWPTR);
    int* cnt     = (int*)((char*)d_ws + OFF_CNT);

    if (ws_size >= NEED_DENSE) {
        bf16* xtbl = (bf16*)((char*)d_ws + OFF_XT);
        bf16* A    = (bf16*)((char*)d_ws + OFF_A);
        int*  srcs = (int*)((char*)d_ws + OFF_SRCS);

        hipMemsetAsync(cnt, 0, (size_t)53248 * sizeof(int), stream);
        nf2bf_kernel<<<1563, 256, 0, stream>>>(nfeats, xtbl);
        hist_kernel<<<1024, 256, 0, stream>>>(dst, cnt);
        scan_kernel<<<1, 1024, 0, stream>>>(cnt, row_ptr);
        gather_kernel<<<2048, 256, 0, stream>>>(efeats, src, dst, cnt, A, srcs);
        msg_agg_dense<<<1024, 256, 0, stream>>>(nfeats, xtbl, A, srcs,
                                                W_msg, b_msg, row_ptr, h_neigh);
    } else if (ws_size >= NEED_CSR) {
        int* eid  = (int*)((char*)d_ws + OFF_EID);
        int* srcs = (int*)((char*)d_ws + OFF_SRCS2);
        hipMemsetAsync(cnt, 0, (size_t)53248 * sizeof(int), stream);
        hist_kernel<<<1024, 256, 0, stream>>>(dst, cnt);
        scan_kernel<<<1, 1024, 0, stream>>>(cnt, row_ptr);
        scatter_kernel<<<1024, 256, 0, stream>>>(src, dst, cnt, eid, srcs);
        msg_agg_kernel<<<1024, 256, 0, stream>>>(nfeats, efeats, W_msg, b_msg,
                                                 row_ptr, eid, srcs, h_neigh);
    } else {
        hipMemsetAsync(h_neigh, 0, (size_t)N_NODES * NDIM_OUT * sizeof(float), stream);
        edge_msg_kernel<<<768, 256, 0, stream>>>(nfeats, efeats, W_msg, b_msg,
                                                 src, dst, h_neigh);
    }

    apply_kernel<<<782, 256, 0, stream>>>(nfeats, h_neigh, W_apply, b_apply, d_out);
}

// Round 5
// 669.549 us; speedup vs baseline: 1.4660x; 1.4660x over previous
//
#include <hip/hip_runtime.h>
#include <hip/hip_bf16.h>

#define N_NODES  50000
#define N_EDGES  800000
#define NDIM_IN  64
#define EDIMS    64
#define NDIM_OUT 128

typedef __bf16 bf16;
typedef bf16  bf16x8 __attribute__((ext_vector_type(8)));
typedef float f32x4  __attribute__((ext_vector_type(4)));

// ---------------------------------------------------------------------------
// Runtime dtype detection (harness dtype is ambiguous; we guard both ways).
// ---------------------------------------------------------------------------
__device__ __forceinline__ bool detect_f32(const void* nfeats) {
    const unsigned short* w = (const unsigned short*)nfeats;
    for (int i = 0; i < 64; i += 2) {
        const int e = (w[i] >> 7) & 0xFF;
        if (e < 100 || e > 134) return true;
    }
    return false;
}
__device__ __forceinline__ bool detect_i64(const int* p) {
    for (int i = 1; i < 64; i += 2) if (p[i] != 0) return false;
    return true;
}

__device__ __forceinline__ bf16x8 load8(const void* p, long off, bool f32) {
    if (f32) {
        const float* q = (const float*)p + off;
        const f32x4 a = *(const f32x4*)q;
        const f32x4 b = *(const f32x4*)(q + 4);
        bf16x8 r;
        #pragma unroll
        for (int u = 0; u < 4; ++u) { r[u] = (bf16)a[u]; r[4 + u] = (bf16)b[u]; }
        return r;
    }
    return *(const bf16x8*)((const bf16*)p + off);
}
__device__ __forceinline__ float loadf(const void* p, long i, bool f32) {
    return f32 ? ((const float*)p)[i] : (float)((const bf16*)p)[i];
}
__device__ __forceinline__ void storef(void* p, long i, float v, bool f32) {
    if (f32) ((float*)p)[i] = v; else ((bf16*)p)[i] = (bf16)v;
}

// ---------------------------------------------------------------------------
// nfeats -> bf16 table (coalesced convert). agg gathers x-fragments from this
// 6.4 MB (L2-resident) table; gather no longer touches nfeats at all.
// ---------------------------------------------------------------------------
__global__ __launch_bounds__(256) void nf2bf_kernel(const void* __restrict__ nfeats,
                                                    bf16* __restrict__ tbl) {
    __shared__ int s_flags;
    if (threadIdx.x == 0) s_flags = detect_f32(nfeats) ? 1 : 0;
    __syncthreads();
    const bool f32 = (s_flags & 1) != 0;
    const int total  = N_NODES * 64 / 8;          // 400000 chunks of 8
    const int stride = gridDim.x * blockDim.x;
    for (int i = blockIdx.x * blockDim.x + threadIdx.x; i < total; i += stride)
        *(bf16x8*)(tbl + (size_t)i * 8) = load8(nfeats, (long)i * 8, f32);
}

// ---------------------------------------------------------------------------
// CSR build step 1: histogram over dst.
// ---------------------------------------------------------------------------
__global__ __launch_bounds__(256) void hist_kernel(const int* __restrict__ dst,
                                                   int* __restrict__ cnt) {
    __shared__ int s_ish;
    if (threadIdx.x == 0) s_ish = detect_i64(dst) ? 1 : 0;
    __syncthreads();
    const int ish = s_ish;
    const int stride = gridDim.x * blockDim.x;
    for (int e = blockIdx.x * blockDim.x + threadIdx.x; e < N_EDGES; e += stride)
        atomicAdd(&cnt[dst[(long)e << ish]], 1);
}

// ---------------------------------------------------------------------------
// CSR build step 2: exclusive scan of counts (padded to 53248 = 1024*52 ints,
// pad region pre-zeroed). int4 loads + shfl wave scans. Writes row_ptr[] and
// resets cnt[] in place to the running cursor for the gather pass.
// ---------------------------------------------------------------------------
__global__ __launch_bounds__(1024) void scan_kernel(int* __restrict__ cnt,
                                                    int* __restrict__ row_ptr) {
    __shared__ int sw[16];
    const int t    = threadIdx.x;
    const int lane = t & 63;
    const int w    = t >> 6;
    const int base = t * 52;

    int sum = 0;
    #pragma unroll
    for (int j = 0; j < 13; ++j) {
        const int4 q = *(const int4*)(cnt + base + j * 4);
        sum += q.x + q.y + q.z + q.w;
    }
    int s = sum;
    #pragma unroll
    for (int off = 1; off < 64; off <<= 1) {
        const int u = __shfl_up(s, off, 64);
        if (lane >= off) s += u;
    }
    if (lane == 63) sw[w] = s;
    __syncthreads();
    if (t < 16) {
        int x = sw[t];
        #pragma unroll
        for (int off = 1; off < 16; off <<= 1) {
            const int u = __shfl_up(x, off, 16);
            if ((t & 15) >= off) x += u;
        }
        sw[t] = x;
    }
    __syncthreads();
    int run = (w > 0 ? sw[w - 1] : 0) + (s - sum);
    #pragma unroll
    for (int j = 0; j < 13; ++j) {
        const int4 q = *(const int4*)(cnt + base + j * 4);
        int4 r;
        r.x = run; run += q.x;
        r.y = run; run += q.y;
        r.z = run; run += q.z;
        r.w = run; run += q.w;
        *(int4*)(row_ptr + base + j * 4) = r;
        *(int4*)(cnt     + base + j * 4) = r;
    }
}

// ---------------------------------------------------------------------------
// CSR build step 3: permute efeats into CSR order (128 B bf16 rows) and
// record srcs[] in CSR order. 8 lanes per edge -> every A store is a full
// 128 B line (no partial-line RMW). nfeats no longer gathered here.
// ---------------------------------------------------------------------------
__global__ __launch_bounds__(256) void gather_kernel(
    const void* __restrict__ efeats,
    const int*  __restrict__ src,
    const int*  __restrict__ dst,
    int*        __restrict__ cursor,
    bf16*       __restrict__ A,
    int*        __restrict__ srcs)
{
    __shared__ int s_flags;
    const int tid = threadIdx.x;
    if (tid == 0)
        s_flags = (detect_f32(efeats) ? 1 : 0) | (detect_i64(dst) ? 2 : 0);
    __syncthreads();
    const bool f32 = (s_flags & 1) != 0;
    const int  ish = (s_flags & 2) ? 1 : 0;

    const int lane = tid & 63;
    const int wave = tid >> 6;
    const int q    = lane & 7;    // 16 B chunk of the 128 B output row
    const int ei   = lane >> 3;   // edge within group of 8

    const int ngroups = N_EDGES / 8;          // 100000 exact
    const int nw      = gridDim.x * 4;
    for (int g = blockIdx.x * 4 + wave; g < ngroups; g += nw) {
        const int e = g * 8 + ei;
        int pos = 0, s_ = 0;
        if (q == 0) {
            pos = atomicAdd(&cursor[dst[(long)e << ish]], 1);
            s_  = src[(long)e << ish];
        }
        pos = __shfl(pos, lane & 56, 64);

        const bf16x8 v = load8(efeats, (long)e * 64 + q * 8, f32);
        *(bf16x8*)(A + (size_t)pos * 64 + q * 8) = v;
        if (q == 0) srcs[pos] = s_;
    }
}

// ---------------------------------------------------------------------------
// Dense fused message + aggregate, 4-node batched prefetch.
// Each wave owns a CONTIGUOUS range of ~13 nodes (contiguous A-slots, row_ptr,
// srcs, h_neigh). Per batch of 4 nodes: issue ALL 16 independent frag loads
// first (4-deep memory-level parallelism), then compute the 4 nodes
// back-to-back. No launch_bounds VGPR cap (round-4's (256,4) cap caused the
// 1.6 GB scratch-spill regression: VGPR 64, FETCH 960 MB).
// ---------------------------------------------------------------------------
__global__ __launch_bounds__(256) void msg_agg_dense(
    const void* __restrict__ nfeats,      // only for dtype detection
    const bf16* __restrict__ xtbl,        // [N][64] bf16
    const bf16* __restrict__ A,           // [E][64] bf16, CSR order
    const int*  __restrict__ srcs,        // [E] src id, CSR order
    const void* __restrict__ W_msg,
    const void* __restrict__ b_msg,
    const int*  __restrict__ row_ptr,     // padded: [50000..53247] == N_EDGES
    float*      __restrict__ h_neigh)
{
    __shared__ bf16  sWT[128 * 136];      // [n][k], stride 272 B
    __shared__ float sB[128];
    __shared__ int   s_flags;

    const int tid = threadIdx.x;
    if (tid == 0) s_flags = detect_f32(nfeats) ? 1 : 0;
    __syncthreads();
    const bool f32 = (s_flags & 1) != 0;

    // k-strided staging: task -> (n = task&127, kb8 = task>>7), one b128 write
    #pragma unroll
    for (int it = 0; it < 8; ++it) {
        const int task = it * 256 + tid;
        const int n    = task & 127;
        const int kb8  = task >> 7;       // 0..15
        bf16x8 w;
        #pragma unroll
        for (int j = 0; j < 8; ++j)
            w[j] = (bf16)loadf(W_msg, (long)(kb8 * 8 + j) * 128 + n, f32);
        *(bf16x8*)(sWT + n * 136 + kb8 * 8) = w;
    }
    if (tid < 128) sB[tid] = loadf(b_msg, tid, f32);
    __syncthreads();

    const int wave = tid >> 6;
    const int lane = tid & 63;
    const int m    = lane & 15;
    const int quad = lane >> 4;

    const int G     = gridDim.x * 4;                 // total waves
    const int gw    = blockIdx.x * 4 + wave;
    const int D     = (N_NODES + G - 1) / G;         // nodes per wave (~13)
    const int start = gw * D;
    const int vend  = (start + D < N_NODES) ? (start + D) : N_NODES;

    for (int vb = start; vb < vend; vb += 4) {
        // headers for up to 4 nodes (row_ptr padded region is safe to read)
        int rp[5];
        #pragma unroll
        for (int j = 0; j < 5; ++j) rp[j] = row_ptr[vb + j];

        int bg[4], dg[4], sl[4];
        bf16x8 fa0[4], fa1[4], fx0[4], fx1[4];

        // ---- issue all 16 frag loads (4 nodes x 4 frags), independent ----
        #pragma unroll
        for (int j = 0; j < 4; ++j) {
            const bool act = (vb + j) < vend;
            int beg = rp[j];
            int deg = act ? (rp[j + 1] - beg) : 0;
            bg[j] = beg; dg[j] = deg;
            int s_l = beg + (m < deg ? m : 0);
            s_l = s_l < N_EDGES ? s_l : N_EDGES - 1;
            s_l = s_l > 0 ? s_l : 0;
            sl[j] = s_l;
            fa0[j] = *(const bf16x8*)(A + (size_t)s_l * 64 + quad * 8);
            fa1[j] = *(const bf16x8*)(A + (size_t)s_l * 64 + 32 + quad * 8);
            int s = srcs[s_l];
            s = ((unsigned)s < N_NODES) ? s : 0;
            fx0[j] = *(const bf16x8*)(xtbl + (size_t)s * 64 + quad * 8);
            fx1[j] = *(const bf16x8*)(xtbl + (size_t)s * 64 + 32 + quad * 8);
        }

        // ---- compute the 4 nodes back-to-back ----
        #pragma unroll
        for (int j = 0; j < 4; ++j) {
            const int beg = bg[j];
            const int deg = dg[j];

            float hacc[8] = {0.f, 0.f, 0.f, 0.f, 0.f, 0.f, 0.f, 0.f};

            // tile 0 (common case: deg <= 16) from prefetched frags
            #pragma unroll
            for (int t = 0; t < 8; ++t) {
                f32x4 acc = {0.f, 0.f, 0.f, 0.f};
                const bf16* bp = sWT + (t * 16 + m) * 136 + quad * 8;
                acc = __builtin_amdgcn_mfma_f32_16x16x32_bf16(fx0[j], *(const bf16x8*)(bp      ), acc, 0, 0, 0);
                acc = __builtin_amdgcn_mfma_f32_16x16x32_bf16(fx1[j], *(const bf16x8*)(bp +  32), acc, 0, 0, 0);
                acc = __builtin_amdgcn_mfma_f32_16x16x32_bf16(fa0[j], *(const bf16x8*)(bp +  64), acc, 0, 0, 0);
                acc = __builtin_amdgcn_mfma_f32_16x16x32_bf16(fa1[j], *(const bf16x8*)(bp +  96), acc, 0, 0, 0);
                const float bias = sB[t * 16 + m];
                float part = 0.f;
                #pragma unroll
                for (int i = 0; i < 4; ++i) {
                    float val = acc[i] + bias;
                    val = val > 0.f ? val : 0.f;
                    if (quad * 4 + i < deg) part += val;
                }
                hacc[t] += part;
            }

            // extra tiles (deg > 16), loaded on demand (verified r4 path)
            for (int T = 1; T * 16 < deg; ++T) {
                const int r0 = T * 16;
                const int sx = (r0 + m < deg) ? (beg + r0 + m) : beg;
                const int s  = srcs[sx];
                const bf16x8 c2 = *(const bf16x8*)(A + (size_t)sx * 64 + quad * 8);
                const bf16x8 c3 = *(const bf16x8*)(A + (size_t)sx * 64 + 32 + quad * 8);
                const bf16x8 c0 = *(const bf16x8*)(xtbl + (size_t)s * 64 + quad * 8);
                const bf16x8 c1 = *(const bf16x8*)(xtbl + (size_t)s * 64 + 32 + quad * 8);
                #pragma unroll
                for (int t = 0; t < 8; ++t) {
                    f32x4 acc = {0.f, 0.f, 0.f, 0.f};
                    const bf16* bp = sWT + (t * 16 + m) * 136 + quad * 8;
                    acc = __builtin_amdgcn_mfma_f32_16x16x32_bf16(c0, *(const bf16x8*)(bp      ), acc, 0, 0, 0);
                    acc = __builtin_amdgcn_mfma_f32_16x16x32_bf16(c1, *(const bf16x8*)(bp +  32), acc, 0, 0, 0);
                    acc = __builtin_amdgcn_mfma_f32_16x16x32_bf16(c2, *(const bf16x8*)(bp +  64), acc, 0, 0, 0);
                    acc = __builtin_amdgcn_mfma_f32_16x16x32_bf16(c3, *(const bf16x8*)(bp +  96), acc, 0, 0, 0);
                    const float bias = sB[t * 16 + m];
                    float part = 0.f;
                    #pragma unroll
                    for (int i = 0; i < 4; ++i) {
                        float val = acc[i] + bias;
                        val = val > 0.f ? val : 0.f;
                        if (r0 + quad * 4 + i < deg) part += val;
                    }
                    hacc[t] += part;
                }
            }

            // cross-quad column reduction + coalesced store
            #pragma unroll
            for (int t = 0; t < 8; ++t) {
                float s = hacc[t];
                s += __shfl_xor(s, 16, 64);
                s += __shfl_xor(s, 32, 64);
                hacc[t] = s;
            }
            if (vb + j < vend) {
                const float lo = quad < 2 ? (quad == 0 ? hacc[0] : hacc[1])
                                          : (quad == 2 ? hacc[2] : hacc[3]);
                const float hi = quad < 2 ? (quad == 0 ? hacc[4] : hacc[5])
                                          : (quad == 2 ? hacc[6] : hacc[7]);
                h_neigh[(size_t)(vb + j) * 128 + lane]      = lo;
                h_neigh[(size_t)(vb + j) * 128 + 64 + lane] = hi;
            }
        }
    }
}

// ---------------------------------------------------------------------------
// Fallback CSR path (verified round-1): scatter edge ids, gather in msg_agg.
// ---------------------------------------------------------------------------
__global__ __launch_bounds__(256) void scatter_kernel(const int* __restrict__ src,
                                                      const int* __restrict__ dst,
                                                      int* __restrict__ cursor,
                                                      int* __restrict__ eid,
                                                      int* __restrict__ srcs) {
    __shared__ int s_ish;
    if (threadIdx.x == 0) s_ish = detect_i64(dst) ? 1 : 0;
    __syncthreads();
    const int ish = s_ish;
    const int stride = gridDim.x * blockDim.x;
    for (int e = blockIdx.x * blockDim.x + threadIdx.x; e < N_EDGES; e += stride) {
        const int d = dst[(long)e << ish];
        const int pos = atomicAdd(&cursor[d], 1);
        eid[pos]  = e;
        srcs[pos] = src[(long)e << ish];
    }
}

__global__ __launch_bounds__(256) void msg_agg_kernel(
    const void* __restrict__ nfeats,
    const void* __restrict__ efeats,
    const void* __restrict__ W_msg,
    const void* __restrict__ b_msg,
    const int*  __restrict__ row_ptr,
    const int*  __restrict__ eid,
    const int*  __restrict__ srcs,
    float*      __restrict__ h_neigh)
{
    __shared__ bf16 sWT[128 * 136];
    __shared__ int s_flags;

    const int tid = threadIdx.x;
    if (tid == 0) s_flags = detect_f32(nfeats) ? 1 : 0;
    __syncthreads();
    const bool f32 = (s_flags & 1) != 0;

    #pragma unroll
    for (int it = 0; it < 8; ++it) {
        const int task = it * 256 + tid;
        const int k = task >> 4;
        const int c = task & 15;
        const bf16x8 w = load8(W_msg, (long)k * 128 + c * 8, f32);
        #pragma unroll
        for (int u = 0; u < 8; ++u) sWT[(c * 8 + u) * 136 + k] = w[u];
    }
    __syncthreads();

    const int wave = tid >> 6;
    const int lane = tid & 63;
    const int m    = lane & 15;
    const int quad = lane >> 4;

    float bias[8];
    #pragma unroll
    for (int t = 0; t < 8; ++t) bias[t] = loadf(b_msg, t * 16 + m, f32);

    const int wstride = gridDim.x * 4;
    for (int v = blockIdx.x * 4 + wave; v < N_NODES; v += wstride) {
        const int beg = row_ptr[v];
        const int deg = row_ptr[v + 1] - beg;

        float hacc[8] = {0.f, 0.f, 0.f, 0.f, 0.f, 0.f, 0.f, 0.f};

        for (int T = 0; T * 16 < deg; ++T) {
            const int r0 = T * 16;
            const int sl = (r0 + m < deg) ? (beg + r0 + m) : beg;
            const int s  = srcs[sl];
            const int e  = eid[sl];

            bf16x8 a[4];
            a[0] = load8(nfeats, (long)s * 64 +      quad * 8, f32);
            a[1] = load8(nfeats, (long)s * 64 + 32 + quad * 8, f32);
            a[2] = load8(efeats, (long)e * 64 +      quad * 8, f32);
            a[3] = load8(efeats, (long)e * 64 + 32 + quad * 8, f32);

            #pragma unroll
            for (int t = 0; t < 8; ++t) {
                f32x4 acc = {0.f, 0.f, 0.f, 0.f};
                const bf16* bp = sWT + (t * 16 + m) * 136 + quad * 8;
                #pragma unroll
                for (int kb = 0; kb < 4; ++kb)
                    acc = __builtin_amdgcn_mfma_f32_16x16x32_bf16(
                              a[kb], *(const bf16x8*)(bp + kb * 32), acc, 0, 0, 0);
                float part = 0.f;
                #pragma unroll
                for (int i = 0; i < 4; ++i) {
                    float val = acc[i] + bias[t];
                    val = val > 0.f ? val : 0.f;
                    if (r0 + quad * 4 + i < deg) part += val;
                }
                hacc[t] += part;
            }
        }

        #pragma unroll
        for (int t = 0; t < 8; ++t) {
            float s = hacc[t];
            s += __shfl_xor(s, 16, 64);
            s += __shfl_xor(s, 32, 64);
            hacc[t] = s;
        }

        const float lo = quad < 2 ? (quad == 0 ? hacc[0] : hacc[1])
                                  : (quad == 2 ? hacc[2] : hacc[3]);
        const float hi = quad < 2 ? (quad == 0 ? hacc[4] : hacc[5])
                                  : (quad == 2 ? hacc[6] : hacc[7]);
        h_neigh[(size_t)v * 128 + lane]      = lo;
        h_neigh[(size_t)v * 128 + 64 + lane] = hi;
    }
}

// ---------------------------------------------------------------------------
// Last-resort fallback (verified round-0): per-edge messages + fp32 atomics.
// ---------------------------------------------------------------------------
__global__ __launch_bounds__(256) void edge_msg_kernel(
    const void* __restrict__ nfeats,
    const void* __restrict__ efeats,
    const void* __restrict__ W_msg,
    const void* __restrict__ b_msg,
    const int*  __restrict__ src,
    const int*  __restrict__ dst,
    float*      __restrict__ h_neigh)
{
    __shared__ bf16 sWT[128 * 136];
    __shared__ int s_flags;

    const int tid = threadIdx.x;
    if (tid == 0)
        s_flags = (detect_f32(nfeats) ? 1 : 0) | (detect_i64(dst) ? 2 : 0);
    __syncthreads();
    const bool f32 = (s_flags & 1) != 0;
    const int  ish = (s_flags & 2) ? 1 : 0;

    #pragma unroll
    for (int it = 0; it < 8; ++it) {
        const int task = it * 256 + tid;
        const int k = task >> 4;
        const int c = task & 15;
        const bf16x8 w = load8(W_msg, (long)k * 128 + c * 8, f32);
        #pragma unroll
        for (int u = 0; u < 8; ++u) sWT[(c * 8 + u) * 136 + k] = w[u];
    }
    __syncthreads();

    const int wave = tid >> 6;
    const int lane = tid & 63;
    const int m    = lane & 15;
    const int quad = lane >> 4;

    const int nchunks = N_EDGES / 64;
    for (int chunk = blockIdx.x; chunk < nchunks; chunk += gridDim.x) {
        const int ebase = chunk * 64 + wave * 16;
        const int e_m   = ebase + m;
        const int s     = src[(long)e_m << ish];

        bf16x8 a[4];
        a[0] = load8(nfeats, (long)s   * 64 +      quad * 8, f32);
        a[1] = load8(nfeats, (long)s   * 64 + 32 + quad * 8, f32);
        a[2] = load8(efeats, (long)e_m * 64 +      quad * 8, f32);
        a[3] = load8(efeats, (long)e_m * 64 + 32 + quad * 8, f32);

        int drow[4];
        #pragma unroll
        for (int i = 0; i < 4; ++i)
            drow[i] = dst[(long)(ebase + quad * 4 + i) << ish] * 128;

        #pragma unroll
        for (int t = 0; t < 8; ++t) {
            f32x4 acc = {0.f, 0.f, 0.f, 0.f};
            const bf16* bp = sWT + (t * 16 + m) * 136 + quad * 8;
            #pragma unroll
            for (int kb = 0; kb < 4; ++kb)
                acc = __builtin_amdgcn_mfma_f32_16x16x32_bf16(
                          a[kb], *(const bf16x8*)(bp + kb * 32), acc, 0, 0, 0);
            const int   n    = t * 16 + m;
            const float bias = loadf(b_msg, n, f32);
            #pragma unroll
            for (int i = 0; i < 4; ++i) {
                float v = acc[i] + bias;
                v = v > 0.f ? v : 0.f;
                unsafeAtomicAdd(h_neigh + drow[i] + n, v);
            }
        }
    }
}

// ---------------------------------------------------------------------------
// Kernel B: out = relu([nfeats, h_neigh] @ W_apply + b_apply), K=192.
// (unchanged verified version)
// ---------------------------------------------------------------------------
__global__ __launch_bounds__(256) void apply_kernel(
    const void*  __restrict__ nfeats,
    const float* __restrict__ h_neigh,
    const void*  __restrict__ W_apply,
    const void*  __restrict__ b_apply,
    void*        __restrict__ out)
{
    __shared__ bf16 sWT[128 * 200];   // [n][k], k<192, stride 400 B
    __shared__ int s_flags;

    const int tid = threadIdx.x;
    if (tid == 0) s_flags = detect_f32(nfeats) ? 1 : 0;
    __syncthreads();
    const bool f32 = (s_flags & 1) != 0;

    // k-strided staging: 3072 tasks = 128 n x 24 kb8-blocks
    #pragma unroll
    for (int it = 0; it < 12; ++it) {
        const int task = it * 256 + tid;
        const int n    = task & 127;
        const int kb8  = task >> 7;       // 0..23
        bf16x8 w;
        #pragma unroll
        for (int j = 0; j < 8; ++j)
            w[j] = (bf16)loadf(W_apply, (long)(kb8 * 8 + j) * 128 + n, f32);
        *(bf16x8*)(sWT + n * 200 + kb8 * 8) = w;
    }
    __syncthreads();

    const int wave = tid >> 6;
    const int lane = tid & 63;
    const int m    = lane & 15;
    const int quad = lane >> 4;

    const int nchunks = (N_NODES + 63) / 64;
    for (int chunk = blockIdx.x; chunk < nchunks; chunk += gridDim.x) {
        const int nbase = chunk * 64 + wave * 16;
        const int nm  = nbase + m;
        const int nmc = nm < N_NODES ? nm : N_NODES - 1;

        bf16x8 a[6];
        a[0] = load8(nfeats, (long)nmc * 64 +      quad * 8, f32);
        a[1] = load8(nfeats, (long)nmc * 64 + 32 + quad * 8, f32);
        #pragma unroll
        for (int kb = 0; kb < 4; ++kb) {
            const float* hp = h_neigh + (size_t)nmc * 128 + kb * 32 + quad * 8;
            const f32x4 p = *(const f32x4*)(hp);
            const f32x4 q = *(const f32x4*)(hp + 4);
            bf16x8 r;
            #pragma unroll
            for (int u = 0; u < 4; ++u) { r[u] = (bf16)p[u]; r[4 + u] = (bf16)q[u]; }
            a[2 + kb] = r;
        }

        #pragma unroll
        for (int t = 0; t < 8; ++t) {
            f32x4 acc = {0.f, 0.f, 0.f, 0.f};
            const bf16* bp = sWT + (t * 16 + m) * 200 + quad * 8;
            #pragma unroll
            for (int kb = 0; kb < 6; ++kb)
                acc = __builtin_amdgcn_mfma_f32_16x16x32_bf16(
                          a[kb], *(const bf16x8*)(bp + kb * 32), acc, 0, 0, 0);
            const int   n    = t * 16 + m;
            const float bias = loadf(b_apply, n, f32);
            #pragma unroll
            for (int i = 0; i < 4; ++i) {
                const int row = nbase + quad * 4 + i;
                if (row < N_NODES) {
                    float v = acc[i] + bias;
                    v = v > 0.f ? v : 0.f;
                    storef(out, (long)row * 128 + n, v, f32);
                }
            }
        }
    }
}

extern "C" void kernel_launch(void* const* d_in, const int* in_sizes, int n_in,
                              void* d_out, int out_size, void* d_ws, size_t ws_size,
                              hipStream_t stream) {
    const void* nfeats  = d_in[0];
    const void* efeats  = d_in[1];
    const void* W_msg   = d_in[2];
    const void* b_msg   = d_in[3];
    const void* W_apply = d_in[4];
    const void* b_apply = d_in[5];
    const int*  src     = (const int*)d_in[6];
    const int*  dst     = (const int*)d_in[7];

    float* h_neigh = (float*)d_ws;                        // 25,600,000 B

    // workspace layout (256B-aligned blocks)
    const size_t SZ_PAD     = 213248;                     // 53248 ints, padded
    const size_t OFF_ROWPTR = 25600000;
    const size_t OFF_CNT    = OFF_ROWPTR + SZ_PAD;        // counts -> cursor
    const size_t OFF_XT     = OFF_CNT + SZ_PAD;           // bf16 nfeats table
    const size_t SZ_XT      = (size_t)N_NODES * 64 * 2;   // 6.4 MB
    const size_t OFF_A      = OFF_XT + SZ_XT;             // permuted efeats
    const size_t SZ_A       = (size_t)N_EDGES * 64 * 2;   // 102.4 MB
    const size_t OFF_SRCS   = OFF_A + SZ_A;               // CSR-ordered src
    const size_t NEED_DENSE = OFF_SRCS + 3200000;         // ~138 MB
    const size_t OFF_EID    = OFF_XT;                     // CSR fallback path
    const size_t OFF_SRCS2  = OFF_EID + 3200000;
    const size_t NEED_CSR   = OFF_SRCS2 + 3200000;        // 32.4 MB

    int* row_ptr = (int*)((char*)d_ws + OFF_ROWPTR);
    int* cnt     = (int*)((char*)d_ws + OFF_CNT);

    if (ws_size >= NEED_DENSE) {
        bf16* xtbl = (bf16*)((char*)d_ws + OFF_XT);
        bf16* A    = (bf16*)((char*)d_ws + OFF_A);
        int*  srcs = (int*)((char*)d_ws + OFF_SRCS);

        hipMemsetAsync(cnt, 0, (size_t)53248 * sizeof(int), stream);
        nf2bf_kernel<<<1563, 256, 0, stream>>>(nfeats, xtbl);
        hist_kernel<<<1024, 256, 0, stream>>>(dst, cnt);
        scan_kernel<<<1, 1024, 0, stream>>>(cnt, row_ptr);
        gather_kernel<<<2048, 256, 0, stream>>>(efeats, src, dst, cnt, A, srcs);
        msg_agg_dense<<<1024, 256, 0, stream>>>(nfeats, xtbl, A, srcs,
                                                W_msg, b_msg, row_ptr, h_neigh);
    } else if (ws_size >= NEED_CSR) {
        int* eid  = (int*)((char*)d_ws + OFF_EID);
        int* srcs = (int*)((char*)d_ws + OFF_SRCS2);
        hipMemsetAsync(cnt, 0, (size_t)53248 * sizeof(int), stream);
        hist_kernel<<<1024, 256, 0, stream>>>(dst, cnt);
        scan_kernel<<<1, 1024, 0, stream>>>(cnt, row_ptr);
        scatter_kernel<<<1024, 256, 0, stream>>>(src, dst, cnt, eid, srcs);
        msg_agg_kernel<<<1024, 256, 0, stream>>>(nfeats, efeats, W_msg, b_msg,
                                                 row_ptr, eid, srcs, h_neigh);
    } else {
        hipMemsetAsync(h_neigh, 0, (size_t)N_NODES * NDIM_OUT * sizeof(float), stream);
        edge_msg_kernel<<<768, 256, 0, stream>>>(nfeats, efeats, W_msg, b_msg,
                                                 src, dst, h_neigh);
    }

    apply_kernel<<<782, 256, 0, stream>>>(nfeats, h_neigh, W_apply, b_apply, d_out);
}

// Round 6
// 610.623 us; speedup vs baseline: 1.6074x; 1.0965x over previous
//
#include <hip/hip_runtime.h>
#include <hip/hip_bf16.h>

#define N_NODES  50000
#define N_EDGES  800000
#define NDIM_IN  64
#define EDIMS    64
#define NDIM_OUT 128

typedef __bf16 bf16;
typedef bf16  bf16x8 __attribute__((ext_vector_type(8)));
typedef float f32x4  __attribute__((ext_vector_type(4)));

// ---------------------------------------------------------------------------
// Runtime dtype detection (harness dtype is ambiguous; we guard both ways).
// ---------------------------------------------------------------------------
__device__ __forceinline__ bool detect_f32(const void* nfeats) {
    const unsigned short* w = (const unsigned short*)nfeats;
    for (int i = 0; i < 64; i += 2) {
        const int e = (w[i] >> 7) & 0xFF;
        if (e < 100 || e > 134) return true;
    }
    return false;
}
__device__ __forceinline__ bool detect_i64(const int* p) {
    for (int i = 1; i < 64; i += 2) if (p[i] != 0) return false;
    return true;
}

__device__ __forceinline__ bf16x8 load8(const void* p, long off, bool f32) {
    if (f32) {
        const float* q = (const float*)p + off;
        const f32x4 a = *(const f32x4*)q;
        const f32x4 b = *(const f32x4*)(q + 4);
        bf16x8 r;
        #pragma unroll
        for (int u = 0; u < 4; ++u) { r[u] = (bf16)a[u]; r[4 + u] = (bf16)b[u]; }
        return r;
    }
    return *(const bf16x8*)((const bf16*)p + off);
}
__device__ __forceinline__ float loadf(const void* p, long i, bool f32) {
    return f32 ? ((const float*)p)[i] : (float)((const bf16*)p)[i];
}
__device__ __forceinline__ void storef(void* p, long i, float v, bool f32) {
    if (f32) ((float*)p)[i] = v; else ((bf16*)p)[i] = (bf16)v;
}

// ---------------------------------------------------------------------------
// prep: nfeats -> bf16 table (blocks [0,512)) + dst histogram (blocks >=512).
// Merged to cut one serial dispatch; work types are block-uniform.
// ---------------------------------------------------------------------------
__global__ __launch_bounds__(256) void prep_kernel(const void* __restrict__ nfeats,
                                                   bf16* __restrict__ tbl,
                                                   const int* __restrict__ dst,
                                                   int* __restrict__ cnt,
                                                   const int do_tbl) {
    __shared__ int s_flags;
    if (threadIdx.x == 0)
        s_flags = (detect_f32(nfeats) ? 1 : 0) | (detect_i64(dst) ? 2 : 0);
    __syncthreads();
    const bool f32 = (s_flags & 1) != 0;
    const int  ish = (s_flags & 2) ? 1 : 0;
    const int CONV = 512;
    if ((int)blockIdx.x < CONV) {
        if (!do_tbl) return;
        const int total  = N_NODES * 64 / 8;      // 400000 chunks of 8
        const int stride = CONV * 256;
        for (int i = blockIdx.x * 256 + threadIdx.x; i < total; i += stride)
            *(bf16x8*)(tbl + (size_t)i * 8) = load8(nfeats, (long)i * 8, f32);
    } else {
        const int nb     = gridDim.x - CONV;
        const int stride = nb * 256;
        for (int e = (blockIdx.x - CONV) * 256 + threadIdx.x; e < N_EDGES; e += stride)
            atomicAdd(&cnt[dst[(long)e << ish]], 1);
    }
}

// standalone hist (used by fallback paths only)
__global__ __launch_bounds__(256) void hist_kernel(const int* __restrict__ dst,
                                                   int* __restrict__ cnt) {
    __shared__ int s_ish;
    if (threadIdx.x == 0) s_ish = detect_i64(dst) ? 1 : 0;
    __syncthreads();
    const int ish = s_ish;
    const int stride = gridDim.x * blockDim.x;
    for (int e = blockIdx.x * blockDim.x + threadIdx.x; e < N_EDGES; e += stride)
        atomicAdd(&cnt[dst[(long)e << ish]], 1);
}

// ---------------------------------------------------------------------------
// Exclusive scan of counts (padded to 53248 = 1024*52 ints, pad pre-zeroed).
// Writes row_ptr[] (fallback path) and resets cnt[] in place to the cursor.
// ---------------------------------------------------------------------------
__global__ __launch_bounds__(1024) void scan_kernel(int* __restrict__ cnt,
                                                    int* __restrict__ row_ptr) {
    __shared__ int sw[16];
    const int t    = threadIdx.x;
    const int lane = t & 63;
    const int w    = t >> 6;
    const int base = t * 52;

    int sum = 0;
    #pragma unroll
    for (int j = 0; j < 13; ++j) {
        const int4 q = *(const int4*)(cnt + base + j * 4);
        sum += q.x + q.y + q.z + q.w;
    }
    int s = sum;
    #pragma unroll
    for (int off = 1; off < 64; off <<= 1) {
        const int u = __shfl_up(s, off, 64);
        if (lane >= off) s += u;
    }
    if (lane == 63) sw[w] = s;
    __syncthreads();
    if (t < 16) {
        int x = sw[t];
        #pragma unroll
        for (int off = 1; off < 16; off <<= 1) {
            const int u = __shfl_up(x, off, 16);
            if ((t & 15) >= off) x += u;
        }
        sw[t] = x;
    }
    __syncthreads();
    int run = (w > 0 ? sw[w - 1] : 0) + (s - sum);
    #pragma unroll
    for (int j = 0; j < 13; ++j) {
        const int4 q = *(const int4*)(cnt + base + j * 4);
        int4 r;
        r.x = run; run += q.x;
        r.y = run; run += q.y;
        r.z = run; run += q.z;
        r.w = run; run += q.w;
        *(int4*)(row_ptr + base + j * 4) = r;
        *(int4*)(cnt     + base + j * 4) = r;
    }
}

// ---------------------------------------------------------------------------
// Gather: build full 256 B CSR-ordered rows [bf16(nfeats[src]) | bf16(efeats)]
// (verified r3 form: 16 lanes/edge -> full-line stores, no RMW) and record
// nid[pos] = dst node per CSR slot (replaces srcs; feeds the segmented agg).
// ---------------------------------------------------------------------------
__global__ __launch_bounds__(256) void gather_kernel(
    const void* __restrict__ nfsrc,     // bf16 table (tbl=1) or raw nfeats
    const void* __restrict__ efeats,
    const int*  __restrict__ src,
    const int*  __restrict__ dst,
    int*        __restrict__ cursor,
    bf16*       __restrict__ A,
    int*        __restrict__ nid,
    const int   tbl)
{
    __shared__ int s_flags;
    const int tid = threadIdx.x;
    if (tid == 0)
        s_flags = (detect_f32(efeats) ? 1 : 0) | (detect_i64(dst) ? 2 : 0);
    __syncthreads();
    const bool f32 = (s_flags & 1) != 0;
    const int  ish = (s_flags & 2) ? 1 : 0;

    const int lane = tid & 63;
    const int wave = tid >> 6;
    const int q    = lane & 15;   // 16 B chunk of the 256 B output row
    const int ei   = lane >> 4;   // edge within group of 4

    const int ngroups = N_EDGES / 4;          // 200000 exact
    const int nw      = gridDim.x * 4;
    for (int g = blockIdx.x * 4 + wave; g < ngroups; g += nw) {
        const int e = g * 4 + ei;
        int pos = 0, s_ = 0, d = 0;
        if (q == 0) {
            d   = dst[(long)e << ish];
            pos = atomicAdd(&cursor[d], 1);
            s_  = src[(long)e << ish];
        }
        pos = __shfl(pos, lane & 48, 64);
        s_  = __shfl(s_,  lane & 48, 64);

        bf16x8 v;
        if (q < 8) {
            v = tbl ? *(const bf16x8*)((const bf16*)nfsrc + (size_t)s_ * 64 + q * 8)
                    : load8(nfsrc, (long)s_ * 64 + q * 8, f32);
        } else {
            v = load8(efeats, (long)e * 64 + (q - 8) * 8, f32);
        }
        *(bf16x8*)(A + (size_t)pos * 128 + q * 8) = v;
        if (q == 0) nid[pos] = d;
    }
}

// ---------------------------------------------------------------------------
// Window-parallel fused message + segmented aggregate.
// Each wave owns fixed 64-edge windows of the CSR-ordered A (12500 windows,
// perfect balance). ALL load addresses depend only on the window index ->
// zero dependent loads, compiler hoists all 16 A-loads + nid-load per window.
// Segments (node boundaries) come from a 64-bit ballot of nid[]; per segment:
// xor-reduce across quads + ONE write -- plain store for window-interior
// nodes, unsafeAtomicAdd only for the <=2 window-straddling segments.
// Failed-attempt notes: r4 (256,4) cap -> 1.6 GB scratch spill; r5 split-A
// srcs->xtbl chain -> 206 us (pointer-chase, == r1). Both avoided here.
// ---------------------------------------------------------------------------
__global__ __launch_bounds__(256) void msg_agg_dense(
    const void* __restrict__ nfeats,      // dtype detection only
    const bf16* __restrict__ A,           // [E][128] bf16, CSR order
    const int*  __restrict__ nid,         // [E] dst node per CSR slot
    const void* __restrict__ W_msg,
    const void* __restrict__ b_msg,
    float*      __restrict__ h_neigh)     // pre-zeroed
{
    __shared__ bf16  sWT[128 * 136];      // [n][k], stride 272 B
    __shared__ float sB[128];
    __shared__ int   s_flags;

    const int tid = threadIdx.x;
    if (tid == 0) s_flags = detect_f32(nfeats) ? 1 : 0;
    __syncthreads();
    const bool f32 = (s_flags & 1) != 0;

    // k-strided staging: conflict-free b128 LDS writes (verified r3)
    #pragma unroll
    for (int it = 0; it < 8; ++it) {
        const int task = it * 256 + tid;
        const int n    = task & 127;
        const int kb8  = task >> 7;
        bf16x8 w;
        #pragma unroll
        for (int j = 0; j < 8; ++j)
            w[j] = (bf16)loadf(W_msg, (long)(kb8 * 8 + j) * 128 + n, f32);
        *(bf16x8*)(sWT + n * 136 + kb8 * 8) = w;
    }
    if (tid < 128) sB[tid] = loadf(b_msg, tid, f32);
    __syncthreads();

    const int wave = tid >> 6;
    const int lane = tid & 63;
    const int m    = lane & 15;
    const int quad = lane >> 4;

    const int NW     = N_EDGES / 64;              // 12500 exact
    const int stride = gridDim.x * 4;
    for (int win = blockIdx.x * 4 + wave; win < NW; win += stride) {
        const int base = win * 64;
        const int myn  = nid[base + lane];        // one coalesced 256 B load
        const int nxtn = __shfl_down(myn, 1, 64);
        const unsigned long long bmask =
            __ballot((lane == 63) || (myn != nxtn));   // wave-uniform SGPR

        float hacc[8] = {0.f, 0.f, 0.f, 0.f, 0.f, 0.f, 0.f, 0.f};
        int nflush = 0;

        #pragma unroll
        for (int t4 = 0; t4 < 4; ++t4) {
            // 4 streaming b128 loads; address = f(win) only
            const bf16* ap = A + (size_t)(base + t4 * 16 + m) * 128 + quad * 8;
            const bf16x8 a0 = *(const bf16x8*)(ap);
            const bf16x8 a1 = *(const bf16x8*)(ap + 32);
            const bf16x8 a2 = *(const bf16x8*)(ap + 64);
            const bf16x8 a3 = *(const bf16x8*)(ap + 96);

            f32x4 acc[8];
            #pragma unroll
            for (int t = 0; t < 8; ++t) {
                f32x4 c = {0.f, 0.f, 0.f, 0.f};
                const bf16* bp = sWT + (t * 16 + m) * 136 + quad * 8;
                c = __builtin_amdgcn_mfma_f32_16x16x32_bf16(a0, *(const bf16x8*)(bp     ), c, 0, 0, 0);
                c = __builtin_amdgcn_mfma_f32_16x16x32_bf16(a1, *(const bf16x8*)(bp + 32), c, 0, 0, 0);
                c = __builtin_amdgcn_mfma_f32_16x16x32_bf16(a2, *(const bf16x8*)(bp + 64), c, 0, 0, 0);
                c = __builtin_amdgcn_mfma_f32_16x16x32_bf16(a3, *(const bf16x8*)(bp + 96), c, 0, 0, 0);
                const float bias = sB[t * 16 + m];
                #pragma unroll
                for (int i = 0; i < 4; ++i) {     // relu+bias per edge message
                    const float v = c[i] + bias;
                    c[i] = v > 0.f ? v : 0.f;
                }
                acc[t] = c;
            }

            // serial row walk: per-quad accumulate + uniform boundary flushes
            #pragma unroll
            for (int r = 0; r < 16; ++r) {
                if (quad == (r >> 2)) {
                    #pragma unroll
                    for (int t = 0; t < 8; ++t) hacc[t] += acc[t][r & 3];
                }
                const int idx = t4 * 16 + r;      // compile-time constant
                if ((bmask >> idx) & 1ull) {      // wave-uniform branch
                    const int node = __shfl(myn, idx, 64);
                    float f[8];
                    #pragma unroll
                    for (int t = 0; t < 8; ++t) {
                        float s = hacc[t];
                        s += __shfl_xor(s, 16, 64);
                        s += __shfl_xor(s, 32, 64);
                        f[t] = s;
                        hacc[t] = 0.f;
                    }
                    const float lo = quad < 2 ? (quad == 0 ? f[0] : f[1])
                                              : (quad == 2 ? f[2] : f[3]);
                    const float hi = quad < 2 ? (quad == 0 ? f[4] : f[5])
                                              : (quad == 2 ? f[6] : f[7]);
                    float* hp = h_neigh + (size_t)node * 128;
                    if (nflush > 0 && idx < 63) {     // node fully inside window
                        hp[lane]      = lo;
                        hp[64 + lane] = hi;
                    } else {                          // straddles window edge
                        unsafeAtomicAdd(hp + lane,      lo);
                        unsafeAtomicAdd(hp + 64 + lane, hi);
                    }
                    ++nflush;
                }
            }
        }
    }
}

// ---------------------------------------------------------------------------
// Fallback CSR path (verified round-1): scatter edge ids, gather in msg_agg.
// ---------------------------------------------------------------------------
__global__ __launch_bounds__(256) void scatter_kernel(const int* __restrict__ src,
                                                      const int* __restrict__ dst,
                                                      int* __restrict__ cursor,
                                                      int* __restrict__ eid,
                                                      int* __restrict__ srcs) {
    __shared__ int s_ish;
    if (threadIdx.x == 0) s_ish = detect_i64(dst) ? 1 : 0;
    __syncthreads();
    const int ish = s_ish;
    const int stride = gridDim.x * blockDim.x;
    for (int e = blockIdx.x * blockDim.x + threadIdx.x; e < N_EDGES; e += stride) {
        const int d = dst[(long)e << ish];
        const int pos = atomicAdd(&cursor[d], 1);
        eid[pos]  = e;
        srcs[pos] = src[(long)e << ish];
    }
}

__global__ __launch_bounds__(256) void msg_agg_kernel(
    const void* __restrict__ nfeats,
    const void* __restrict__ efeats,
    const void* __restrict__ W_msg,
    const void* __restrict__ b_msg,
    const int*  __restrict__ row_ptr,
    const int*  __restrict__ eid,
    const int*  __restrict__ srcs,
    float*      __restrict__ h_neigh)
{
    __shared__ bf16 sWT[128 * 136];
    __shared__ int s_flags;

    const int tid = threadIdx.x;
    if (tid == 0) s_flags = detect_f32(nfeats) ? 1 : 0;
    __syncthreads();
    const bool f32 = (s_flags & 1) != 0;

    #pragma unroll
    for (int it = 0; it < 8; ++it) {
        const int task = it * 256 + tid;
        const int k = task >> 4;
        const int c = task & 15;
        const bf16x8 w = load8(W_msg, (long)k * 128 + c * 8, f32);
        #pragma unroll
        for (int u = 0; u < 8; ++u) sWT[(c * 8 + u) * 136 + k] = w[u];
    }
    __syncthreads();

    const int wave = tid >> 6;
    const int lane = tid & 63;
    const int m    = lane & 15;
    const int quad = lane >> 4;

    float bias[8];
    #pragma unroll
    for (int t = 0; t < 8; ++t) bias[t] = loadf(b_msg, t * 16 + m, f32);

    const int wstride = gridDim.x * 4;
    for (int v = blockIdx.x * 4 + wave; v < N_NODES; v += wstride) {
        const int beg = row_ptr[v];
        const int deg = row_ptr[v + 1] - beg;

        float hacc[8] = {0.f, 0.f, 0.f, 0.f, 0.f, 0.f, 0.f, 0.f};

        for (int T = 0; T * 16 < deg; ++T) {
            const int r0 = T * 16;
            const int sl = (r0 + m < deg) ? (beg + r0 + m) : beg;
            const int s  = srcs[sl];
            const int e  = eid[sl];

            bf16x8 a[4];
            a[0] = load8(nfeats, (long)s * 64 +      quad * 8, f32);
            a[1] = load8(nfeats, (long)s * 64 + 32 + quad * 8, f32);
            a[2] = load8(efeats, (long)e * 64 +      quad * 8, f32);
            a[3] = load8(efeats, (long)e * 64 + 32 + quad * 8, f32);

            #pragma unroll
            for (int t = 0; t < 8; ++t) {
                f32x4 acc = {0.f, 0.f, 0.f, 0.f};
                const bf16* bp = sWT + (t * 16 + m) * 136 + quad * 8;
                #pragma unroll
                for (int kb = 0; kb < 4; ++kb)
                    acc = __builtin_amdgcn_mfma_f32_16x16x32_bf16(
                              a[kb], *(const bf16x8*)(bp + kb * 32), acc, 0, 0, 0);
                float part = 0.f;
                #pragma unroll
                for (int i = 0; i < 4; ++i) {
                    float val = acc[i] + bias[t];
                    val = val > 0.f ? val : 0.f;
                    if (r0 + quad * 4 + i < deg) part += val;
                }
                hacc[t] += part;
            }
        }

        #pragma unroll
        for (int t = 0; t < 8; ++t) {
            float s = hacc[t];
            s += __shfl_xor(s, 16, 64);
            s += __shfl_xor(s, 32, 64);
            hacc[t] = s;
        }

        const float lo = quad < 2 ? (quad == 0 ? hacc[0] : hacc[1])
                                  : (quad == 2 ? hacc[2] : hacc[3]);
        const float hi = quad < 2 ? (quad == 0 ? hacc[4] : hacc[5])
                                  : (quad == 2 ? hacc[6] : hacc[7]);
        h_neigh[(size_t)v * 128 + lane]      = lo;
        h_neigh[(size_t)v * 128 + 64 + lane] = hi;
    }
}

// ---------------------------------------------------------------------------
// Last-resort fallback (verified round-0): per-edge messages + fp32 atomics.
// ---------------------------------------------------------------------------
__global__ __launch_bounds__(256) void edge_msg_kernel(
    const void* __restrict__ nfeats,
    const void* __restrict__ efeats,
    const void* __restrict__ W_msg,
    const void* __restrict__ b_msg,
    const int*  __restrict__ src,
    const int*  __restrict__ dst,
    float*      __restrict__ h_neigh)
{
    __shared__ bf16 sWT[128 * 136];
    __shared__ int s_flags;

    const int tid = threadIdx.x;
    if (tid == 0)
        s_flags = (detect_f32(nfeats) ? 1 : 0) | (detect_i64(dst) ? 2 : 0);
    __syncthreads();
    const bool f32 = (s_flags & 1) != 0;
    const int  ish = (s_flags & 2) ? 1 : 0;

    #pragma unroll
    for (int it = 0; it < 8; ++it) {
        const int task = it * 256 + tid;
        const int k = task >> 4;
        const int c = task & 15;
        const bf16x8 w = load8(W_msg, (long)k * 128 + c * 8, f32);
        #pragma unroll
        for (int u = 0; u < 8; ++u) sWT[(c * 8 + u) * 136 + k] = w[u];
    }
    __syncthreads();

    const int wave = tid >> 6;
    const int lane = tid & 63;
    const int m    = lane & 15;
    const int quad = lane >> 4;

    const int nchunks = N_EDGES / 64;
    for (int chunk = blockIdx.x; chunk < nchunks; chunk += gridDim.x) {
        const int ebase = chunk * 64 + wave * 16;
        const int e_m   = ebase + m;
        const int s     = src[(long)e_m << ish];

        bf16x8 a[4];
        a[0] = load8(nfeats, (long)s   * 64 +      quad * 8, f32);
        a[1] = load8(nfeats, (long)s   * 64 + 32 + quad * 8, f32);
        a[2] = load8(efeats, (long)e_m * 64 +      quad * 8, f32);
        a[3] = load8(efeats, (long)e_m * 64 + 32 + quad * 8, f32);

        int drow[4];
        #pragma unroll
        for (int i = 0; i < 4; ++i)
            drow[i] = dst[(long)(ebase + quad * 4 + i) << ish] * 128;

        #pragma unroll
        for (int t = 0; t < 8; ++t) {
            f32x4 acc = {0.f, 0.f, 0.f, 0.f};
            const bf16* bp = sWT + (t * 16 + m) * 136 + quad * 8;
            #pragma unroll
            for (int kb = 0; kb < 4; ++kb)
                acc = __builtin_amdgcn_mfma_f32_16x16x32_bf16(
                          a[kb], *(const bf16x8*)(bp + kb * 32), acc, 0, 0, 0);
            const int   n    = t * 16 + m;
            const float bias = loadf(b_msg, n, f32);
            #pragma unroll
            for (int i = 0; i < 4; ++i) {
                float v = acc[i] + bias;
                v = v > 0.f ? v : 0.f;
                unsafeAtomicAdd(h_neigh + drow[i] + n, v);
            }
        }
    }
}

// ---------------------------------------------------------------------------
// Kernel B: out = relu([nfeats, h_neigh] @ W_apply + b_apply), K=192.
// (unchanged verified version)
// ---------------------------------------------------------------------------
__global__ __launch_bounds__(256) void apply_kernel(
    const void*  __restrict__ nfeats,
    const float* __restrict__ h_neigh,
    const void*  __restrict__ W_apply,
    const void*  __restrict__ b_apply,
    void*        __restrict__ out)
{
    __shared__ bf16 sWT[128 * 200];   // [n][k], k<192, stride 400 B
    __shared__ int s_flags;

    const int tid = threadIdx.x;
    if (tid == 0) s_flags = detect_f32(nfeats) ? 1 : 0;
    __syncthreads();
    const bool f32 = (s_flags & 1) != 0;

    #pragma unroll
    for (int it = 0; it < 12; ++it) {
        const int task = it * 256 + tid;
        const int n    = task & 127;
        const int kb8  = task >> 7;       // 0..23
        bf16x8 w;
        #pragma unroll
        for (int j = 0; j < 8; ++j)
            w[j] = (bf16)loadf(W_apply, (long)(kb8 * 8 + j) * 128 + n, f32);
        *(bf16x8*)(sWT + n * 200 + kb8 * 8) = w;
    }
    __syncthreads();

    const int wave = tid >> 6;
    const int lane = tid & 63;
    const int m    = lane & 15;
    const int quad = lane >> 4;

    const int nchunks = (N_NODES + 63) / 64;
    for (int chunk = blockIdx.x; chunk < nchunks; chunk += gridDim.x) {
        const int nbase = chunk * 64 + wave * 16;
        const int nm  = nbase + m;
        const int nmc = nm < N_NODES ? nm : N_NODES - 1;

        bf16x8 a[6];
        a[0] = load8(nfeats, (long)nmc * 64 +      quad * 8, f32);
        a[1] = load8(nfeats, (long)nmc * 64 + 32 + quad * 8, f32);
        #pragma unroll
        for (int kb = 0; kb < 4; ++kb) {
            const float* hp = h_neigh + (size_t)nmc * 128 + kb * 32 + quad * 8;
            const f32x4 p = *(const f32x4*)(hp);
            const f32x4 q = *(const f32x4*)(hp + 4);
            bf16x8 r;
            #pragma unroll
            for (int u = 0; u < 4; ++u) { r[u] = (bf16)p[u]; r[4 + u] = (bf16)q[u]; }
            a[2 + kb] = r;
        }

        #pragma unroll
        for (int t = 0; t < 8; ++t) {
            f32x4 acc = {0.f, 0.f, 0.f, 0.f};
            const bf16* bp = sWT + (t * 16 + m) * 200 + quad * 8;
            #pragma unroll
            for (int kb = 0; kb < 6; ++kb)
                acc = __builtin_amdgcn_mfma_f32_16x16x32_bf16(
                          a[kb], *(const bf16x8*)(bp + kb * 32), acc, 0, 0, 0);
            const int   n    = t * 16 + m;
            const float bias = loadf(b_apply, n, f32);
            #pragma unroll
            for (int i = 0; i < 4; ++i) {
                const int row = nbase + quad * 4 + i;
                if (row < N_NODES) {
                    float v = acc[i] + bias;
                    v = v > 0.f ? v : 0.f;
                    storef(out, (long)row * 128 + n, v, f32);
                }
            }
        }
    }
}

extern "C" void kernel_launch(void* const* d_in, const int* in_sizes, int n_in,
                              void* d_out, int out_size, void* d_ws, size_t ws_size,
                              hipStream_t stream) {
    const void* nfeats  = d_in[0];
    const void* efeats  = d_in[1];
    const void* W_msg   = d_in[2];
    const void* b_msg   = d_in[3];
    const void* W_apply = d_in[4];
    const void* b_apply = d_in[5];
    const int*  src     = (const int*)d_in[6];
    const int*  dst     = (const int*)d_in[7];

    float* h_neigh = (float*)d_ws;                        // 25,600,000 B

    // workspace layout (256B-aligned blocks)
    const size_t SZ_PAD     = 213248;                     // 53248 ints, padded
    const size_t OFF_ROWPTR = 25600000;
    const size_t OFF_CNT    = OFF_ROWPTR + SZ_PAD;        // counts -> cursor
    const size_t OFF_XT     = OFF_CNT + SZ_PAD;           // bf16 nfeats table
    const size_t SZ_XT      = (size_t)N_NODES * 64 * 2;   // 6.4 MB
    const size_t OFF_A      = OFF_XT + SZ_XT;             // full 256B CSR rows
    const size_t SZ_A       = (size_t)N_EDGES * 128 * 2;  // 204.8 MB
    const size_t OFF_NID    = OFF_A + SZ_A;               // dst node per slot
    const size_t NEED_FULL  = OFF_NID + 3200000;          // ~240.4 MB
    const size_t OFF_A2     = OFF_XT;                     // no-table variant
    const size_t OFF_NID2   = OFF_A2 + SZ_A;
    const size_t NEED_NOTBL = OFF_NID2 + 3200000;         // ~234.0 MB
    const size_t OFF_EID    = OFF_XT;                     // CSR fallback path
    const size_t OFF_SRCS2  = OFF_EID + 3200000;
    const size_t NEED_CSR   = OFF_SRCS2 + 3200000;        // 32.4 MB

    int* row_ptr = (int*)((char*)d_ws + OFF_ROWPTR);
    int* cnt     = (int*)((char*)d_ws + OFF_CNT);

    if (ws_size >= NEED_NOTBL) {
        const int tbl = (ws_size >= NEED_FULL) ? 1 : 0;
        bf16* xtbl = (bf16*)((char*)d_ws + OFF_XT);
        bf16* A    = (bf16*)((char*)d_ws + (tbl ? OFF_A   : OFF_A2));
        int*  nid  = (int*)((char*)d_ws + (tbl ? OFF_NID : OFF_NID2));

        hipMemsetAsync(cnt, 0, (size_t)53248 * sizeof(int), stream);
        hipMemsetAsync(h_neigh, 0, (size_t)N_NODES * NDIM_OUT * sizeof(float), stream);
        prep_kernel<<<1536, 256, 0, stream>>>(nfeats, xtbl, dst, cnt, tbl);
        scan_kernel<<<1, 1024, 0, stream>>>(cnt, row_ptr);
        gather_kernel<<<2048, 256, 0, stream>>>(tbl ? (const void*)xtbl : nfeats,
                                                efeats, src, dst, cnt, A, nid, tbl);
        msg_agg_dense<<<1024, 256, 0, stream>>>(nfeats, A, nid,
                                                W_msg, b_msg, h_neigh);
    } else if (ws_size >= NEED_CSR) {
        int* eid  = (int*)((char*)d_ws + OFF_EID);
        int* srcs = (int*)((char*)d_ws + OFF_SRCS2);
        hipMemsetAsync(cnt, 0, (size_t)53248 * sizeof(int), stream);
        hist_kernel<<<1024, 256, 0, stream>>>(dst, cnt);
        scan_kernel<<<1, 1024, 0, stream>>>(cnt, row_ptr);
        scatter_kernel<<<1024, 256, 0, stream>>>(src, dst, cnt, eid, srcs);
        msg_agg_kernel<<<1024, 256, 0, stream>>>(nfeats, efeats, W_msg, b_msg,
                                                 row_ptr, eid, srcs, h_neigh);
    } else {
        hipMemsetAsync(h_neigh, 0, (size_t)N_NODES * NDIM_OUT * sizeof(float), stream);
        edge_msg_kernel<<<768, 256, 0, stream>>>(nfeats, efeats, W_msg, b_msg,
                                                 src, dst, h_neigh);
    }

    apply_kernel<<<782, 256, 0, stream>>>(nfeats, h_neigh, W_apply, b_apply, d_out);
}